// Round 6
// baseline (306.560 us; speedup 1.0000x reference)
//
#include <hip/hip_runtime.h>
#include <hip/hip_bf16.h>

// B=2, L=2048, D=1024, H=16, dh=64. fp32 in/out.
// out = softmax((qa@Wq/8) @ (ma@Wk)^T + bias) @ (ma@Wv) @ Wo.
// Round 12 (resubmit; prior run died to container infra failure):
// attn = 4 row-groups x 2 key-groups. Wave (r,kk) owns 32 q-rows
// (2 groups of 16 sharing all K/V frag reads) and m-chunks {2kk,2kk+1} only:
// per-wave LDS reads halve at UNCHANGED occupancy (grid 512, 2 blk/CU,
// 16 waves/CU -- R11's mistake was paying for sharing with occupancy).
// No-max softmax partials are additive: key-groups combine via one LDS pass
// (Of[128][68] f32 overlaid on Ks/Vt). GEMMs: R11 config (BM=64 out-proj).

typedef __attribute__((ext_vector_type(8))) short short8;   // 8 x bf16 fragment
typedef __attribute__((ext_vector_type(4))) short short4v;  // 4 x bf16
typedef __attribute__((ext_vector_type(4))) float float4v;  // 4 x f32

#define BATCH 2
#define LSEQ 2048
#define DMODEL 1024
#define NHEADS 16
#define DHEAD 64
#define MROWS 4096   // B*L
#define QKVLD 3072   // fused QKV C leading dim

// ---------------------------------------------------------------------------
// fp32 -> bf16 bulk convert (qa, ma). grid (2048, 2)
// ---------------------------------------------------------------------------
__global__ __launch_bounds__(256)
void convert_kernel(const float* __restrict__ qa, const float* __restrict__ ma,
                    __hip_bfloat16* __restrict__ qo, __hip_bfloat16* __restrict__ mo)
{
    const size_t i = ((size_t)blockIdx.x * 256 + threadIdx.x) * 8;
    const float* src = blockIdx.y ? ma : qa;
    __hip_bfloat16* dst = blockIdx.y ? mo : qo;
    float4 v0 = *reinterpret_cast<const float4*>(src + i);
    float4 v1 = *reinterpret_cast<const float4*>(src + i + 4);
    union { __hip_bfloat16 h[8]; int4 v; } pk;
    pk.h[0] = (__hip_bfloat16)v0.x; pk.h[1] = (__hip_bfloat16)v0.y;
    pk.h[2] = (__hip_bfloat16)v0.z; pk.h[3] = (__hip_bfloat16)v0.w;
    pk.h[4] = (__hip_bfloat16)v1.x; pk.h[5] = (__hip_bfloat16)v1.y;
    pk.h[6] = (__hip_bfloat16)v1.z; pk.h[7] = (__hip_bfloat16)v1.w;
    *reinterpret_cast<int4*>(dst + i) = pk.v;
}

// ---------------------------------------------------------------------------
// Weight transpose+convert: W[K][N] f32 -> Wt[N][K] bf16. 64x64 tiles.
// grid (16, 16, 4): z=0..2 -> Wq/Wk/Wv into concat Wt[3072][1024]; z=3 -> Wo.
// ---------------------------------------------------------------------------
__global__ __launch_bounds__(256)
void transpose_w_kernel(const float* __restrict__ W0, const float* __restrict__ W1,
                        const float* __restrict__ W2, const float* __restrict__ W3,
                        __hip_bfloat16* __restrict__ T0, __hip_bfloat16* __restrict__ T1,
                        __hip_bfloat16* __restrict__ T2, __hip_bfloat16* __restrict__ T3)
{
    __shared__ __hip_bfloat16 T[64][68];   // [k][n]

    const float* W; __hip_bfloat16* D;
    if      (blockIdx.z == 0) { W = W0; D = T0; }
    else if (blockIdx.z == 1) { W = W1; D = T1; }
    else if (blockIdx.z == 2) { W = W2; D = T2; }
    else                      { W = W3; D = T3; }

    const int t  = threadIdx.x;
    const int n0 = blockIdx.x * 64;
    const int k0 = blockIdx.y * 64;

#pragma unroll
    for (int p = 0; p < 4; ++p) {
        const int r = p * 16 + (t >> 4);
        const int c = (t & 15) * 4;
        float4 v = *reinterpret_cast<const float4*>(&W[(size_t)(k0 + r) * DMODEL + n0 + c]);
        union { __hip_bfloat16 h[4]; ushort4 v; } pk;
        pk.h[0] = (__hip_bfloat16)v.x; pk.h[1] = (__hip_bfloat16)v.y;
        pk.h[2] = (__hip_bfloat16)v.z; pk.h[3] = (__hip_bfloat16)v.w;
        *reinterpret_cast<ushort4*>(&T[r][c]) = pk.v;
    }
    __syncthreads();
#pragma unroll
    for (int p = 0; p < 2; ++p) {
        const int n  = p * 32 + (t & 31);
        const int kc = (t >> 5) * 8;
        union { __hip_bfloat16 h[8]; int4 v; } pk;
#pragma unroll
        for (int j = 0; j < 8; ++j) pk.h[j] = T[kc + j][n];
        *reinterpret_cast<int4*>(&D[(size_t)(n0 + n) * DMODEL + k0 + kc]) = pk.v;
    }
}

// ---------------------------------------------------------------------------
// bf16 GEMM, B-transposed, m97 structure, templated on BM (128 or 64).
// C[M,N] = alpha * A[M,K] @ Bt[N,K]^T, A = (n0 < nsplit) ? A0 : A1.
// BMx128 tile, BK=64, 4 waves. Staging: global_load_lds dwordx4, linear LDS
// dest, per-lane global source pre-swizzled chunk=(l&7)^(l>>3); frag reads use
// chunk^(row&7). 1D grid (multiple of 8), XCD-chunked m-panels.
// ---------------------------------------------------------------------------
#define GBK 64

template<int BMT>
__global__ __launch_bounds__(256, 2)
void gemm_bt_kernel(const __hip_bfloat16* __restrict__ A0,
                    const __hip_bfloat16* __restrict__ A1, int nsplit,
                    float alpha0, float alpha1,
                    const __hip_bfloat16* __restrict__ Bt,
                    float* __restrict__ Cf, __hip_bfloat16* __restrict__ Cb,
                    int K, int ldc, int nbx)
{
    __shared__ __hip_bfloat16 As[BMT][GBK];
    __shared__ __hip_bfloat16 Bs[128][GBK];

    const int t    = threadIdx.x;
    const int w    = t >> 6;
    const int lane = t & 63;
    const int l15  = lane & 15;
    const int lq   = lane >> 4;
    const int wm   = (w >> 1) * (BMT / 2);
    const int wn   = (w & 1) * 64;
    const int MI   = BMT / 32;           // m-frags per wave

    // XCD-chunked block map: XCD c owns contiguous m-panels, n fast.
    const int nwg  = gridDim.x;
    const int c    = blockIdx.x & 7;
    const int q    = blockIdx.x >> 3;
    const int mper = (nwg >> 3) / nbx;
    const int m0   = (c * mper + q / nbx) * BMT;
    const int n0   = (q % nbx) * 128;

    const __hip_bfloat16* A = (n0 < nsplit) ? A0 : A1;
    const float alpha = (n0 < nsplit) ? alpha0 : alpha1;

    const int lrow = lane >> 3;                    // 0..7
    const int lch  = (lane & 7) ^ lrow;            // pre-swizzled source chunk

    float4v acc[BMT / 32][4];
#pragma unroll
    for (int mi = 0; mi < MI; ++mi)
#pragma unroll
        for (int ni = 0; ni < 4; ++ni) acc[mi][ni] = (float4v){0.f, 0.f, 0.f, 0.f};

    for (int k0 = 0; k0 < K; k0 += GBK) {
        __syncthreads();
#pragma unroll
        for (int i = 0; i < BMT / 32; ++i) {
            const int rb = (w * (BMT / 32) + i) * 8;
            const int r  = rb + lrow;
            __builtin_amdgcn_global_load_lds(
                (const __attribute__((address_space(1))) void*)
                    (A + (size_t)(m0 + r) * K + k0 + lch * 8),
                (__attribute__((address_space(3))) void*)&As[rb][0], 16, 0, 0);
        }
#pragma unroll
        for (int i = 0; i < 4; ++i) {
            const int rb = (w * 4 + i) * 8;
            const int r  = rb + lrow;
            __builtin_amdgcn_global_load_lds(
                (const __attribute__((address_space(1))) void*)
                    (Bt + (size_t)(n0 + r) * K + k0 + lch * 8),
                (__attribute__((address_space(3))) void*)&Bs[rb][0], 16, 0, 0);
        }
        asm volatile("s_waitcnt vmcnt(0)" ::: "memory");
        __syncthreads();

#pragma unroll
        for (int kh = 0; kh < 2; ++kh) {
            short8 af[BMT / 32], bf[4];
#pragma unroll
            for (int mi = 0; mi < MI; ++mi) {
                const int r = wm + mi * 16 + l15;
                af[mi] = *reinterpret_cast<const short8*>(
                    &As[r][(((kh << 2) | lq) ^ (r & 7)) << 3]);
            }
#pragma unroll
            for (int ni = 0; ni < 4; ++ni) {
                const int r = wn + ni * 16 + l15;
                bf[ni] = *reinterpret_cast<const short8*>(
                    &Bs[r][(((kh << 2) | lq) ^ (r & 7)) << 3]);
            }
#pragma unroll
            for (int mi = 0; mi < MI; ++mi)
#pragma unroll
                for (int ni = 0; ni < 4; ++ni)
                    acc[mi][ni] = __builtin_amdgcn_mfma_f32_16x16x32_bf16(
                        af[mi], bf[ni], acc[mi][ni], 0, 0, 0);
        }
    }

#pragma unroll
    for (int mi = 0; mi < MI; ++mi)
#pragma unroll
        for (int ni = 0; ni < 4; ++ni)
#pragma unroll
            for (int r = 0; r < 4; ++r) {
                const int row = m0 + wm + mi * 16 + lq * 4 + r;
                const int col = n0 + wn + ni * 16 + l15;
                const float v = acc[mi][ni][r] * alpha;
                if (Cf) Cf[(size_t)row * ldc + col] = v;
                else    Cb[(size_t)row * ldc + col] = (__hip_bfloat16)v;
            }
}

// ---------------------------------------------------------------------------
// MFMA flash attention, swapped-QK, in-register P. Grid 512 (XCD-swizzled),
// 512 threads = 8 waves = 4 row-groups x 2 key-groups. Wave (r,kk) owns
// q-rows [r*32, r*32+32) as 2 groups of 16 sharing all K/V frag reads, and
// m-chunks {2kk, 2kk+1} (keys 64kk..64kk+63) of each 128-key tile.
// Partial o_acc/lsum (no-max softmax => additive) combine via Of[128][68]
// f32 overlaid on Ks/Vt at the end. Occupancy: 2 blk/CU x 8 waves = 16/CU.
// ---------------------------------------------------------------------------
#define KSTR 68
#define PSTR 132

__global__ __launch_bounds__(512, 4)
void attn_mfma_kernel(const __hip_bfloat16* __restrict__ QKV,  // [B*L][3072]
                      const float* __restrict__ bias,
                      __hip_bfloat16* __restrict__ X)          // [B*L][1024]
{
    __shared__ __align__(16) char smem[34816];
    auto Ks = reinterpret_cast<__hip_bfloat16(*)[KSTR]>(smem);          // [128][68]
    auto Vt = reinterpret_cast<__hip_bfloat16(*)[PSTR]>(smem + 17408);  // [64][132]
    auto Of = reinterpret_cast<float(*)[68]>(smem);                     // [128][68]

    const int t   = threadIdx.x;
    const int w   = t >> 6;            // 0..7
    const int r   = w & 3;             // row-group
    const int kk  = w >> 2;            // key-group
    const int l15 = t & 15;
    const int lq  = (t & 63) >> 4;

    // XCD swizzle: pin each (b,h)'s 16 q-tiles to one XCD-class.
    const int bid = blockIdx.x;
    const int r8  = bid & 7;
    const int j   = bid >> 3;            // 0..63
    const int bh  = r8 + 8 * (j >> 4);   // 0..31
    const int q0  = (j & 15) * 128;
    const int b   = bh >> 4;
    const int h   = bh & 15;

    const __hip_bfloat16* Kb = QKV + (size_t)b * LSEQ * QKVLD + 1024 + h * DHEAD;
    const __hip_bfloat16* Vb = Kb + 1024;

    // Q fragments for both row-groups (B-operand: col = l15), loop-invariant
    short8 aq[2][2];
#pragma unroll
    for (int g = 0; g < 2; ++g) {
        const __hip_bfloat16* qrow = QKV +
            (size_t)(b * LSEQ + q0 + r * 32 + g * 16 + l15) * QKVLD + h * DHEAD + lq * 8;
        aq[g][0] = *reinterpret_cast<const short8*>(qrow);
        aq[g][1] = *reinterpret_cast<const short8*>(qrow + 32);
    }

    // bias row bases: this lane's q-rows, key offset lq*4
    const float* bp0 = bias + (size_t)(q0 + r * 32 + l15) * LSEQ + lq * 4;
    const float* bp1 = bp0 + (size_t)16 * LSEQ;

    float lsum[2] = {0.f, 0.f};
    float4v o_acc[2][4];
#pragma unroll
    for (int g = 0; g < 2; ++g)
#pragma unroll
        for (int n = 0; n < 4; ++n) o_acc[g][n] = (float4v){0.f, 0.f, 0.f, 0.f};

    // staging: thread t stages key (t>>2), dh chunk (t&3)*16, row-group a=t&3
    const int skey = t >> 2;           // 0..127
    const int sdh  = (t & 3) * 16;
    const int a    = t & 3;
    const int cblk = ((skey >> 5) << 2) | ((skey >> 2) & 3);
    const int vcol = (((cblk ^ (a << 2)) << 3)) | ((((skey >> 4) & 1) << 2)) | (skey & 3);

    int4 pk0, pk1, pv0, pv1;
    {
        const __hip_bfloat16* ks = Kb + (size_t)skey * QKVLD + sdh;
        pk0 = *reinterpret_cast<const int4*>(ks);
        pk1 = *reinterpret_cast<const int4*>(ks + 8);
        const __hip_bfloat16* vs = Vb + (size_t)skey * QKVLD + sdh;
        pv0 = *reinterpret_cast<const int4*>(vs);
        pv1 = *reinterpret_cast<const int4*>(vs + 8);
    }

    for (int kt = 0; kt < LSEQ / 128; ++kt) {
        const int k0 = kt * 128;
        __syncthreads();   // previous tile's Ks/Vt consumers done
        *reinterpret_cast<int4*>(&Ks[skey][sdh])     = pk0;
        *reinterpret_cast<int4*>(&Ks[skey][sdh + 8]) = pk1;
        {
            const __hip_bfloat16* vp0 = reinterpret_cast<const __hip_bfloat16*>(&pv0);
            const __hip_bfloat16* vp1 = reinterpret_cast<const __hip_bfloat16*>(&pv1);
#pragma unroll
            for (int jj = 0; jj < 8; ++jj) Vt[sdh + jj][vcol]     = vp0[jj];
#pragma unroll
            for (int jj = 0; jj < 8; ++jj) Vt[sdh + 8 + jj][vcol] = vp1[jj];
        }
        {
            const int knext = (kt + 1 < LSEQ / 128) ? k0 + 128 : k0;
            const __hip_bfloat16* ks = Kb + (size_t)(knext + skey) * QKVLD + sdh;
            pk0 = *reinterpret_cast<const int4*>(ks);
            pk1 = *reinterpret_cast<const int4*>(ks + 8);
            const __hip_bfloat16* vs = Vb + (size_t)(knext + skey) * QKVLD + sdh;
            pv0 = *reinterpret_cast<const int4*>(vs);
            pv1 = *reinterpret_cast<const int4*>(vs + 8);
        }
        __syncthreads();

        // this wave's 2 m-chunks (32 keys each): QK -> exp/pack -> PV
#pragma unroll
        for (int mm = 0; mm < 2; ++mm) {
            const int m = kk * 2 + mm;
            short8 bkA0 = *reinterpret_cast<const short8*>(&Ks[(2*m)    *16 + l15][lq * 8]);
            short8 bkA1 = *reinterpret_cast<const short8*>(&Ks[(2*m)    *16 + l15][32 + lq * 8]);
            short8 bkB0 = *reinterpret_cast<const short8*>(&Ks[(2*m + 1)*16 + l15][lq * 8]);
            short8 bkB1 = *reinterpret_cast<const short8*>(&Ks[(2*m + 1)*16 + l15][32 + lq * 8]);

            float4v sA[2], sB[2];
#pragma unroll
            for (int g = 0; g < 2; ++g) {
                sA[g] = (float4v){0.f, 0.f, 0.f, 0.f};
                sB[g] = (float4v){0.f, 0.f, 0.f, 0.f};
            }
            __builtin_amdgcn_s_setprio(1);
#pragma unroll
            for (int g = 0; g < 2; ++g) {
                sA[g] = __builtin_amdgcn_mfma_f32_16x16x32_bf16(bkA0, aq[g][0], sA[g], 0, 0, 0);
                sA[g] = __builtin_amdgcn_mfma_f32_16x16x32_bf16(bkA1, aq[g][1], sA[g], 0, 0, 0);
                sB[g] = __builtin_amdgcn_mfma_f32_16x16x32_bf16(bkB0, aq[g][0], sB[g], 0, 0, 0);
                sB[g] = __builtin_amdgcn_mfma_f32_16x16x32_bf16(bkB1, aq[g][1], sB[g], 0, 0, 0);
            }
            __builtin_amdgcn_s_setprio(0);

            // p = exp(s + bias); lane-local pack into PV B-fragment.
            // pf element jj: key 32m + (jj>>2)*16 + 4lq + (jj&3)
            short8 pf[2];
#pragma unroll
            for (int g = 0; g < 2; ++g) {
                const float* bp = g ? bp1 : bp0;
                float4v bvA = *reinterpret_cast<const float4v*>(bp + k0 + 32 * m);
                float4v bvB = *reinterpret_cast<const float4v*>(bp + k0 + 32 * m + 16);
                union { __hip_bfloat16 hh[8]; short8 v; } pp;
#pragma unroll
                for (int e = 0; e < 4; ++e) {
                    const float ev = __expf(sA[g][e] + bvA[e]);
                    lsum[g] += ev;
                    pp.hh[e] = (__hip_bfloat16)ev;
                }
#pragma unroll
                for (int e = 0; e < 4; ++e) {
                    const float ev = __expf(sB[g][e] + bvB[e]);
                    lsum[g] += ev;
                    pp.hh[4 + e] = (__hip_bfloat16)ev;
                }
                pf[g] = pp.v;
            }

            // V^T fragments, slot order: one b128 per n, shared by g
            short8 vt[4];
#pragma unroll
            for (int n = 0; n < 4; ++n)
                vt[n] = *reinterpret_cast<const short8*>(
                    &Vt[n * 16 + l15][((m * 4 + lq) ^ (n << 2)) << 3]);

            __builtin_amdgcn_s_setprio(1);
#pragma unroll
            for (int g = 0; g < 2; ++g)
#pragma unroll
                for (int n = 0; n < 4; ++n)
                    o_acc[g][n] = __builtin_amdgcn_mfma_f32_16x16x32_bf16(
                        vt[n], pf[g], o_acc[g][n], 0, 0, 0);
            __builtin_amdgcn_s_setprio(0);
        }
    }

    // intra-wave l reduce across the 4 lq groups of each q-row
#pragma unroll
    for (int g = 0; g < 2; ++g) {
        lsum[g] += __shfl_xor(lsum[g], 16);
        lsum[g] += __shfl_xor(lsum[g], 32);
    }

    // cross-key-group combine via LDS (Of overlays Ks/Vt; last consumers done)
    __syncthreads();
    if (kk == 1) {
#pragma unroll
        for (int g = 0; g < 2; ++g) {
            const int row = r * 32 + g * 16 + l15;
#pragma unroll
            for (int n = 0; n < 4; ++n)
                *reinterpret_cast<float4v*>(&Of[row][n * 16 + lq * 4]) = o_acc[g][n];
            if (lq == 0) Of[row][64] = lsum[g];
        }
    }
    __syncthreads();
    if (kk == 0) {
#pragma unroll
        for (int g = 0; g < 2; ++g) {
            const int row = r * 32 + g * 16 + l15;
#pragma unroll
            for (int n = 0; n < 4; ++n)
                o_acc[g][n] += *reinterpret_cast<const float4v*>(&Of[row][n * 16 + lq * 4]);
            const float inv = 1.f / (lsum[g] + Of[row][64]);
            __hip_bfloat16* dst =
                X + (size_t)(b * LSEQ + q0 + row) * DMODEL + h * DHEAD + lq * 4;
#pragma unroll
            for (int n = 0; n < 4; ++n) {
                union { __hip_bfloat16 hh[4]; short4v v; } o;
#pragma unroll
                for (int e = 0; e < 4; ++e)
                    o.hh[e] = (__hip_bfloat16)(o_acc[g][n][e] * inv);
                *reinterpret_cast<short4v*>(dst + n * 16) = o.v;
            }
        }
    }
}

// ---------------------------------------------------------------------------
extern "C" void kernel_launch(void* const* d_in, const int* in_sizes, int n_in,
                              void* d_out, int out_size, void* d_ws, size_t ws_size,
                              hipStream_t stream)
{
    const float* qa   = (const float*)d_in[0];
    const float* ma   = (const float*)d_in[1];
    const float* bias = (const float*)d_in[2];
    const float* Wq   = (const float*)d_in[3];
    const float* Wk   = (const float*)d_in[4];
    const float* Wv   = (const float*)d_in[5];
    const float* Wo   = (const float*)d_in[6];
    float* out = (float*)d_out;

    // ws layout (48 MB): [0,8) qa16/Xw | [8,16) ma16 | [16,22) Wt | [22,24) Wot
    //                    | [24,48) QKVw[4096][3072]
    char* wsb = (char*)d_ws;
    __hip_bfloat16* qa16 = (__hip_bfloat16*)(wsb);
    __hip_bfloat16* ma16 = (__hip_bfloat16*)(wsb + (8u << 20));
    __hip_bfloat16* Wt   = (__hip_bfloat16*)(wsb + (16u << 20));
    __hip_bfloat16* Wot  = (__hip_bfloat16*)(wsb + (22u << 20));
    __hip_bfloat16* QKVw = (__hip_bfloat16*)(wsb + (24u << 20));
    __hip_bfloat16* Xw   = qa16;   // qa16 dead after QKV GEMM

    convert_kernel<<<dim3(MROWS * DMODEL / (256 * 8), 2), 256, 0, stream>>>(
        qa, ma, qa16, ma16);

    transpose_w_kernel<<<dim3(16, 16, 4), 256, 0, stream>>>(
        Wq, Wk, Wv, Wo,
        Wt, Wt + (size_t)DMODEL * DMODEL, Wt + 2 * (size_t)DMODEL * DMODEL, Wot);

    // QKV: M=4096, N=3072, K=1024. BM=128: grid 768 (24 n x 32 m).
    gemm_bt_kernel<128><<<dim3(768), 256, 0, stream>>>(
        qa16, ma16, DMODEL, 0.125f, 1.0f, Wt, nullptr, QKVw, DMODEL, QKVLD, 24);

    attn_mfma_kernel<<<dim3(512), 512, 0, stream>>>(QKVw, bias, Xw);

    // out-proj: M=4096, N=1024, K=1024. BM=64: grid 512 (8 n x 64 m).
    gemm_bt_kernel<64><<<dim3(512), 256, 0, stream>>>(
        Xw, Xw, DMODEL + 1, 1.0f, 1.0f, Wot, out, nullptr, DMODEL, DMODEL, 8);
}

// Round 7
// 235.210 us; speedup vs baseline: 1.3033x; 1.3033x over previous
//
#include <hip/hip_runtime.h>
#include <hip/hip_bf16.h>

// B=2, L=2048, D=1024, H=16, dh=64. fp32 in/out.
// out = softmax((qa@Wq/8) @ (ma@Wk)^T + bias) @ (ma@Wv) @ Wo.
// Round 13: revert attn to R9 work split (8 waves x 16 q-rows, full keys,
// grid 512, 2 blk/CU -- the measured best; R11/R12 sharing variants lost).
// New: double-buffered K/V LDS, ONE barrier per tile; tile t+1 LDS writes +
// t+2 global prefetch overlap tile t compute (write latency off the critical
// path, no vmcnt(0) drain -- per-wave reg deps only). GEMMs: R10/R4 config.

typedef __attribute__((ext_vector_type(8))) short short8;   // 8 x bf16 fragment
typedef __attribute__((ext_vector_type(4))) short short4v;  // 4 x bf16
typedef __attribute__((ext_vector_type(4))) float float4v;  // 4 x f32

#define BATCH 2
#define LSEQ 2048
#define DMODEL 1024
#define NHEADS 16
#define DHEAD 64
#define MROWS 4096   // B*L
#define QKVLD 3072   // fused QKV C leading dim

// ---------------------------------------------------------------------------
// fp32 -> bf16 bulk convert (qa, ma). grid (2048, 2)
// ---------------------------------------------------------------------------
__global__ __launch_bounds__(256)
void convert_kernel(const float* __restrict__ qa, const float* __restrict__ ma,
                    __hip_bfloat16* __restrict__ qo, __hip_bfloat16* __restrict__ mo)
{
    const size_t i = ((size_t)blockIdx.x * 256 + threadIdx.x) * 8;
    const float* src = blockIdx.y ? ma : qa;
    __hip_bfloat16* dst = blockIdx.y ? mo : qo;
    float4 v0 = *reinterpret_cast<const float4*>(src + i);
    float4 v1 = *reinterpret_cast<const float4*>(src + i + 4);
    union { __hip_bfloat16 h[8]; int4 v; } pk;
    pk.h[0] = (__hip_bfloat16)v0.x; pk.h[1] = (__hip_bfloat16)v0.y;
    pk.h[2] = (__hip_bfloat16)v0.z; pk.h[3] = (__hip_bfloat16)v0.w;
    pk.h[4] = (__hip_bfloat16)v1.x; pk.h[5] = (__hip_bfloat16)v1.y;
    pk.h[6] = (__hip_bfloat16)v1.z; pk.h[7] = (__hip_bfloat16)v1.w;
    *reinterpret_cast<int4*>(dst + i) = pk.v;
}

// ---------------------------------------------------------------------------
// Weight transpose+convert: W[K][N] f32 -> Wt[N][K] bf16. 64x64 tiles.
// grid (16, 16, 4): z=0..2 -> Wq/Wk/Wv into concat Wt[3072][1024]; z=3 -> Wo.
// ---------------------------------------------------------------------------
__global__ __launch_bounds__(256)
void transpose_w_kernel(const float* __restrict__ W0, const float* __restrict__ W1,
                        const float* __restrict__ W2, const float* __restrict__ W3,
                        __hip_bfloat16* __restrict__ T0, __hip_bfloat16* __restrict__ T1,
                        __hip_bfloat16* __restrict__ T2, __hip_bfloat16* __restrict__ T3)
{
    __shared__ __hip_bfloat16 T[64][68];   // [k][n]

    const float* W; __hip_bfloat16* D;
    if      (blockIdx.z == 0) { W = W0; D = T0; }
    else if (blockIdx.z == 1) { W = W1; D = T1; }
    else if (blockIdx.z == 2) { W = W2; D = T2; }
    else                      { W = W3; D = T3; }

    const int t  = threadIdx.x;
    const int n0 = blockIdx.x * 64;
    const int k0 = blockIdx.y * 64;

#pragma unroll
    for (int p = 0; p < 4; ++p) {
        const int r = p * 16 + (t >> 4);
        const int c = (t & 15) * 4;
        float4 v = *reinterpret_cast<const float4*>(&W[(size_t)(k0 + r) * DMODEL + n0 + c]);
        union { __hip_bfloat16 h[4]; ushort4 v; } pk;
        pk.h[0] = (__hip_bfloat16)v.x; pk.h[1] = (__hip_bfloat16)v.y;
        pk.h[2] = (__hip_bfloat16)v.z; pk.h[3] = (__hip_bfloat16)v.w;
        *reinterpret_cast<ushort4*>(&T[r][c]) = pk.v;
    }
    __syncthreads();
#pragma unroll
    for (int p = 0; p < 2; ++p) {
        const int n  = p * 32 + (t & 31);
        const int kc = (t >> 5) * 8;
        union { __hip_bfloat16 h[8]; int4 v; } pk;
#pragma unroll
        for (int j = 0; j < 8; ++j) pk.h[j] = T[kc + j][n];
        *reinterpret_cast<int4*>(&D[(size_t)(n0 + n) * DMODEL + k0 + kc]) = pk.v;
    }
}

// ---------------------------------------------------------------------------
// bf16 GEMM, B-transposed, m97 structure, templated on BM (128 or 64).
// C[M,N] = alpha * A[M,K] @ Bt[N,K]^T, A = (n0 < nsplit) ? A0 : A1.
// BMx128 tile, BK=64, 4 waves. Staging: global_load_lds dwordx4, linear LDS
// dest, per-lane global source pre-swizzled chunk=(l&7)^(l>>3); frag reads use
// chunk^(row&7). 1D grid (multiple of 8), XCD-chunked m-panels.
// ---------------------------------------------------------------------------
#define GBK 64

template<int BMT>
__global__ __launch_bounds__(256, 2)
void gemm_bt_kernel(const __hip_bfloat16* __restrict__ A0,
                    const __hip_bfloat16* __restrict__ A1, int nsplit,
                    float alpha0, float alpha1,
                    const __hip_bfloat16* __restrict__ Bt,
                    float* __restrict__ Cf, __hip_bfloat16* __restrict__ Cb,
                    int K, int ldc, int nbx)
{
    __shared__ __hip_bfloat16 As[BMT][GBK];
    __shared__ __hip_bfloat16 Bs[128][GBK];

    const int t    = threadIdx.x;
    const int w    = t >> 6;
    const int lane = t & 63;
    const int l15  = lane & 15;
    const int lq   = lane >> 4;
    const int wm   = (w >> 1) * (BMT / 2);
    const int wn   = (w & 1) * 64;
    const int MI   = BMT / 32;           // m-frags per wave

    // XCD-chunked block map: XCD c owns contiguous m-panels, n fast.
    const int nwg  = gridDim.x;
    const int c    = blockIdx.x & 7;
    const int q    = blockIdx.x >> 3;
    const int mper = (nwg >> 3) / nbx;
    const int m0   = (c * mper + q / nbx) * BMT;
    const int n0   = (q % nbx) * 128;

    const __hip_bfloat16* A = (n0 < nsplit) ? A0 : A1;
    const float alpha = (n0 < nsplit) ? alpha0 : alpha1;

    const int lrow = lane >> 3;                    // 0..7
    const int lch  = (lane & 7) ^ lrow;            // pre-swizzled source chunk

    float4v acc[BMT / 32][4];
#pragma unroll
    for (int mi = 0; mi < MI; ++mi)
#pragma unroll
        for (int ni = 0; ni < 4; ++ni) acc[mi][ni] = (float4v){0.f, 0.f, 0.f, 0.f};

    for (int k0 = 0; k0 < K; k0 += GBK) {
        __syncthreads();
#pragma unroll
        for (int i = 0; i < BMT / 32; ++i) {
            const int rb = (w * (BMT / 32) + i) * 8;
            const int r  = rb + lrow;
            __builtin_amdgcn_global_load_lds(
                (const __attribute__((address_space(1))) void*)
                    (A + (size_t)(m0 + r) * K + k0 + lch * 8),
                (__attribute__((address_space(3))) void*)&As[rb][0], 16, 0, 0);
        }
#pragma unroll
        for (int i = 0; i < 4; ++i) {
            const int rb = (w * 4 + i) * 8;
            const int r  = rb + lrow;
            __builtin_amdgcn_global_load_lds(
                (const __attribute__((address_space(1))) void*)
                    (Bt + (size_t)(n0 + r) * K + k0 + lch * 8),
                (__attribute__((address_space(3))) void*)&Bs[rb][0], 16, 0, 0);
        }
        asm volatile("s_waitcnt vmcnt(0)" ::: "memory");
        __syncthreads();

#pragma unroll
        for (int kh = 0; kh < 2; ++kh) {
            short8 af[BMT / 32], bf[4];
#pragma unroll
            for (int mi = 0; mi < MI; ++mi) {
                const int r = wm + mi * 16 + l15;
                af[mi] = *reinterpret_cast<const short8*>(
                    &As[r][(((kh << 2) | lq) ^ (r & 7)) << 3]);
            }
#pragma unroll
            for (int ni = 0; ni < 4; ++ni) {
                const int r = wn + ni * 16 + l15;
                bf[ni] = *reinterpret_cast<const short8*>(
                    &Bs[r][(((kh << 2) | lq) ^ (r & 7)) << 3]);
            }
#pragma unroll
            for (int mi = 0; mi < MI; ++mi)
#pragma unroll
                for (int ni = 0; ni < 4; ++ni)
                    acc[mi][ni] = __builtin_amdgcn_mfma_f32_16x16x32_bf16(
                        af[mi], bf[ni], acc[mi][ni], 0, 0, 0);
        }
    }

#pragma unroll
    for (int mi = 0; mi < MI; ++mi)
#pragma unroll
        for (int ni = 0; ni < 4; ++ni)
#pragma unroll
            for (int r = 0; r < 4; ++r) {
                const int row = m0 + wm + mi * 16 + lq * 4 + r;
                const int col = n0 + wn + ni * 16 + l15;
                const float v = acc[mi][ni][r] * alpha;
                if (Cf) Cf[(size_t)row * ldc + col] = v;
                else    Cb[(size_t)row * ldc + col] = (__hip_bfloat16)v;
            }
}

// ---------------------------------------------------------------------------
// MFMA flash attention, swapped-QK, in-register P, double-buffered LDS.
// Grid 512 (XCD-swizzled), 512 threads = 8 waves; wave w owns q-rows
// [w*16, w*16+16) (R9 split -- measured best). S^T = mfma(K-frag, Q-frag):
// lane (lq,l15) holds keys {16c+4lq+r} for q-row l15; bias loads float4.
// PV slot permutation slot(lq,j) <-> key 32m+(j>>2)*16+4lq+(j&3); Vt in slot
// order, ^(a<<2)/^(n<<2) bank swizzle. ONE barrier per tile: iter kt writes
// tile kt+1 into buf cur^1 (regs), issues t+2 prefetch, computes buf cur.
// 2 blk/CU x 8 waves = 16 waves/CU; LDS 68608 B (2 x 34304).
// ---------------------------------------------------------------------------
#define KSTR 68
#define PSTR 132
#define NT (LSEQ / 128)

__global__ __launch_bounds__(512, 4)
void attn_mfma_kernel(const __hip_bfloat16* __restrict__ QKV,  // [B*L][3072]
                      const float* __restrict__ bias,
                      __hip_bfloat16* __restrict__ X)          // [B*L][1024]
{
    __shared__ __hip_bfloat16 Ks[2][128][KSTR];    // 2 x 17408 B
    __shared__ __hip_bfloat16 Vt[2][64][PSTR];     // 2 x 16896 B

    const int t   = threadIdx.x;
    const int w   = t >> 6;            // 0..7
    const int l15 = t & 15;
    const int lq  = (t & 63) >> 4;

    // XCD swizzle: pin each (b,h)'s 16 q-tiles to one XCD-class.
    const int bid = blockIdx.x;
    const int r8  = bid & 7;
    const int j   = bid >> 3;            // 0..63
    const int bh  = r8 + 8 * (j >> 4);   // 0..31
    const int q0  = (j & 15) * 128;
    const int b   = bh >> 4;
    const int h   = bh & 15;

    const __hip_bfloat16* Kb = QKV + (size_t)b * LSEQ * QKVLD + 1024 + h * DHEAD;
    const __hip_bfloat16* Vb = Kb + 1024;

    // Q fragments (B-operand: col = l15 -> q-row w*16+l15), loop-invariant
    short8 aq[2];
    {
        const __hip_bfloat16* qrow = QKV +
            (size_t)(b * LSEQ + q0 + w * 16 + l15) * QKVLD + h * DHEAD + lq * 8;
        aq[0] = *reinterpret_cast<const short8*>(qrow);
        aq[1] = *reinterpret_cast<const short8*>(qrow + 32);
    }

    // bias row base: this lane's q-row, key offset lq*4
    const float* bp = bias + (size_t)(q0 + w * 16 + l15) * LSEQ + lq * 4;

    float lsum = 0.f;
    float4v o_acc[4];
#pragma unroll
    for (int n = 0; n < 4; ++n) o_acc[n] = (float4v){0.f, 0.f, 0.f, 0.f};

    // staging: thread t stages key (t>>2), dh chunk (t&3)*16, row-group a=t&3
    const int skey = t >> 2;           // 0..127
    const int sdh  = (t & 3) * 16;
    const int a    = t & 3;
    const int cblk = ((skey >> 5) << 2) | ((skey >> 2) & 3);
    const int vcol = (((cblk ^ (a << 2)) << 3)) | ((((skey >> 4) & 1) << 2)) | (skey & 3);

    int4 pk0, pk1, pv0, pv1;
    // ---- prologue: tile 0 -> regs -> buf 0; tile 1 -> regs ----
    {
        const __hip_bfloat16* ks = Kb + (size_t)skey * QKVLD + sdh;
        pk0 = *reinterpret_cast<const int4*>(ks);
        pk1 = *reinterpret_cast<const int4*>(ks + 8);
        const __hip_bfloat16* vs = Vb + (size_t)skey * QKVLD + sdh;
        pv0 = *reinterpret_cast<const int4*>(vs);
        pv1 = *reinterpret_cast<const int4*>(vs + 8);
    }
    *reinterpret_cast<int4*>(&Ks[0][skey][sdh])     = pk0;
    *reinterpret_cast<int4*>(&Ks[0][skey][sdh + 8]) = pk1;
    {
        const __hip_bfloat16* vp0 = reinterpret_cast<const __hip_bfloat16*>(&pv0);
        const __hip_bfloat16* vp1 = reinterpret_cast<const __hip_bfloat16*>(&pv1);
#pragma unroll
        for (int jj = 0; jj < 8; ++jj) Vt[0][sdh + jj][vcol]     = vp0[jj];
#pragma unroll
        for (int jj = 0; jj < 8; ++jj) Vt[0][sdh + 8 + jj][vcol] = vp1[jj];
    }
    {
        const __hip_bfloat16* ks = Kb + (size_t)(128 + skey) * QKVLD + sdh;
        pk0 = *reinterpret_cast<const int4*>(ks);
        pk1 = *reinterpret_cast<const int4*>(ks + 8);
        const __hip_bfloat16* vs = Vb + (size_t)(128 + skey) * QKVLD + sdh;
        pv0 = *reinterpret_cast<const int4*>(vs);
        pv1 = *reinterpret_cast<const int4*>(vs + 8);
    }
    __syncthreads();

    for (int kt = 0; kt < NT; ++kt) {
        const int cur = kt & 1;
        const int k0  = kt * 128;

        // write tile kt+1 into the other buffer; prefetch tile kt+2 to regs
        if (kt < NT - 1) {
            *reinterpret_cast<int4*>(&Ks[cur ^ 1][skey][sdh])     = pk0;
            *reinterpret_cast<int4*>(&Ks[cur ^ 1][skey][sdh + 8]) = pk1;
            const __hip_bfloat16* vp0 = reinterpret_cast<const __hip_bfloat16*>(&pv0);
            const __hip_bfloat16* vp1 = reinterpret_cast<const __hip_bfloat16*>(&pv1);
#pragma unroll
            for (int jj = 0; jj < 8; ++jj) Vt[cur ^ 1][sdh + jj][vcol]     = vp0[jj];
#pragma unroll
            for (int jj = 0; jj < 8; ++jj) Vt[cur ^ 1][sdh + 8 + jj][vcol] = vp1[jj];
            if (kt < NT - 2) {
                const int knext = k0 + 256;
                const __hip_bfloat16* ks = Kb + (size_t)(knext + skey) * QKVLD + sdh;
                pk0 = *reinterpret_cast<const int4*>(ks);
                pk1 = *reinterpret_cast<const int4*>(ks + 8);
                const __hip_bfloat16* vs = Vb + (size_t)(knext + skey) * QKVLD + sdh;
                pv0 = *reinterpret_cast<const int4*>(vs);
                pv1 = *reinterpret_cast<const int4*>(vs + 8);
            }
        }

        // 4 chunks of 32 keys: QK -> exp/pack -> PV, all register-resident
#pragma unroll
        for (int m = 0; m < 4; ++m) {
            short8 bkA0 = *reinterpret_cast<const short8*>(&Ks[cur][(2*m)    *16 + l15][lq * 8]);
            short8 bkA1 = *reinterpret_cast<const short8*>(&Ks[cur][(2*m)    *16 + l15][32 + lq * 8]);
            short8 bkB0 = *reinterpret_cast<const short8*>(&Ks[cur][(2*m + 1)*16 + l15][lq * 8]);
            short8 bkB1 = *reinterpret_cast<const short8*>(&Ks[cur][(2*m + 1)*16 + l15][32 + lq * 8]);
            float4v bvA = *reinterpret_cast<const float4v*>(bp + k0 + 32 * m);
            float4v bvB = *reinterpret_cast<const float4v*>(bp + k0 + 32 * m + 16);

            float4v sA = (float4v){0.f, 0.f, 0.f, 0.f};
            float4v sB = (float4v){0.f, 0.f, 0.f, 0.f};
            __builtin_amdgcn_s_setprio(1);
            sA = __builtin_amdgcn_mfma_f32_16x16x32_bf16(bkA0, aq[0], sA, 0, 0, 0);
            sA = __builtin_amdgcn_mfma_f32_16x16x32_bf16(bkA1, aq[1], sA, 0, 0, 0);
            sB = __builtin_amdgcn_mfma_f32_16x16x32_bf16(bkB0, aq[0], sB, 0, 0, 0);
            sB = __builtin_amdgcn_mfma_f32_16x16x32_bf16(bkB1, aq[1], sB, 0, 0, 0);
            __builtin_amdgcn_s_setprio(0);

            // p = exp(s + bias); lane-local pack into PV B-fragment.
            // pf element j: key 32m + (j>>2)*16 + 4lq + (j&3)
            union { __hip_bfloat16 hh[8]; short8 v; } pp;
#pragma unroll
            for (int e = 0; e < 4; ++e) {
                const float ev = __expf(sA[e] + bvA[e]);
                lsum += ev;
                pp.hh[e] = (__hip_bfloat16)ev;
            }
#pragma unroll
            for (int e = 0; e < 4; ++e) {
                const float ev = __expf(sB[e] + bvB[e]);
                lsum += ev;
                pp.hh[4 + e] = (__hip_bfloat16)ev;
            }
            const short8 pf = pp.v;

            // V^T fragments, slot order: one b128 per n, ^(n<<2) bank swizzle
            short8 vt[4];
#pragma unroll
            for (int n = 0; n < 4; ++n)
                vt[n] = *reinterpret_cast<const short8*>(
                    &Vt[cur][n * 16 + l15][((m * 4 + lq) ^ (n << 2)) << 3]);

            __builtin_amdgcn_s_setprio(1);
#pragma unroll
            for (int n = 0; n < 4; ++n)
                o_acc[n] = __builtin_amdgcn_mfma_f32_16x16x32_bf16(
                    vt[n], pf, o_acc[n], 0, 0, 0);
            __builtin_amdgcn_s_setprio(0);
        }
        __syncthreads();
    }

    // finalize l across the 4 lq groups sharing each q-row, then store.
    lsum += __shfl_xor(lsum, 16);
    lsum += __shfl_xor(lsum, 32);
    const float inv = 1.f / lsum;
    {
        const int row = q0 + w * 16 + l15;
        __hip_bfloat16* dst = X + (size_t)(b * LSEQ + row) * DMODEL + h * DHEAD + lq * 4;
#pragma unroll
        for (int n = 0; n < 4; ++n) {
            union { __hip_bfloat16 hh[4]; short4v v; } o;
#pragma unroll
            for (int e = 0; e < 4; ++e) o.hh[e] = (__hip_bfloat16)(o_acc[n][e] * inv);
            *reinterpret_cast<short4v*>(dst + n * 16) = o.v;
        }
    }
}

// ---------------------------------------------------------------------------
extern "C" void kernel_launch(void* const* d_in, const int* in_sizes, int n_in,
                              void* d_out, int out_size, void* d_ws, size_t ws_size,
                              hipStream_t stream)
{
    const float* qa   = (const float*)d_in[0];
    const float* ma   = (const float*)d_in[1];
    const float* bias = (const float*)d_in[2];
    const float* Wq   = (const float*)d_in[3];
    const float* Wk   = (const float*)d_in[4];
    const float* Wv   = (const float*)d_in[5];
    const float* Wo   = (const float*)d_in[6];
    float* out = (float*)d_out;

    // ws layout (48 MB): [0,8) qa16/Xw | [8,16) ma16 | [16,22) Wt | [22,24) Wot
    //                    | [24,48) QKVw[4096][3072]
    char* wsb = (char*)d_ws;
    __hip_bfloat16* qa16 = (__hip_bfloat16*)(wsb);
    __hip_bfloat16* ma16 = (__hip_bfloat16*)(wsb + (8u << 20));
    __hip_bfloat16* Wt   = (__hip_bfloat16*)(wsb + (16u << 20));
    __hip_bfloat16* Wot  = (__hip_bfloat16*)(wsb + (22u << 20));
    __hip_bfloat16* QKVw = (__hip_bfloat16*)(wsb + (24u << 20));
    __hip_bfloat16* Xw   = qa16;   // qa16 dead after QKV GEMM

    convert_kernel<<<dim3(MROWS * DMODEL / (256 * 8), 2), 256, 0, stream>>>(
        qa, ma, qa16, ma16);

    transpose_w_kernel<<<dim3(16, 16, 4), 256, 0, stream>>>(
        Wq, Wk, Wv, Wo,
        Wt, Wt + (size_t)DMODEL * DMODEL, Wt + 2 * (size_t)DMODEL * DMODEL, Wot);

    // QKV: M=4096, N=3072, K=1024. BM=128: grid 768 (24 n x 32 m).
    gemm_bt_kernel<128><<<dim3(768), 256, 0, stream>>>(
        qa16, ma16, DMODEL, 0.125f, 1.0f, Wt, nullptr, QKVw, DMODEL, QKVLD, 24);

    attn_mfma_kernel<<<dim3(512), 512, 0, stream>>>(QKVw, bias, Xw);

    // out-proj: M=4096, N=1024, K=1024. BM=64: grid 512 (8 n x 64 m).
    gemm_bt_kernel<64><<<dim3(512), 256, 0, stream>>>(
        Xw, Xw, DMODEL + 1, 1.0f, 1.0f, Wot, out, nullptr, DMODEL, DMODEL, 8);
}